// Round 2
// baseline (336.506 us; speedup 1.0000x reference)
//
#include <hip/hip_runtime.h>
#include <stdint.h>

#define BPU    5
#define NBINS  200
#define GLEN   195   // NBINS - BPU
#define HLEN   196   // NBINS - BPU + 1
#define KH     256   // raw key-histogram bins
#define KOFF   128   // key = floor(x*5) + 128

// ---------------- helpers ----------------

// order-preserving float -> uint map (ascending)
__device__ inline uint32_t fkey(float f) {
    uint32_t u = __float_as_uint(f);
    return (u & 0x80000000u) ? ~u : (u | 0x80000000u);
}
__device__ inline float funkey(uint32_t k) {
    return (k & 0x80000000u) ? __uint_as_float(k ^ 0x80000000u)
                             : __uint_as_float(~k);
}

__device__ inline void bump(float v, uint32_t* lh) {
    float kf = floorf(v * 5.0f);
    kf = fminf(fmaxf(kf, (float)(-KOFF)), (float)(KH - 1 - KOFF));
    atomicAdd(&lh[(int)kf + KOFF], 1u);
}

// ---------------- kernel 0: init ws (ws re-poisoned 0xAA every call) ---------

__global__ __launch_bounds__(256) void k_init(uint32_t* khist, uint32_t* minkey,
                                              uint32_t* done1, uint32_t* done2,
                                              double* acc) {
    int t = threadIdx.x;
    khist[t] = 0u;
    if (t == 0) { *minkey = 0xFFFFFFFFu; *done1 = 0u; *done2 = 0u; *acc = 0.0; }
}

// ---- kernel 1: fused min + shifted histogram; last block builds tables ------

__global__ __launch_bounds__(256) void k_min_hist(const float4* __restrict__ x4, int n4,
                                                  uint32_t* __restrict__ khist,
                                                  uint32_t* __restrict__ minkey,
                                                  uint32_t* __restrict__ done1,
                                                  float2*  __restrict__ gha,
                                                  float*   __restrict__ vmn_out,
                                                  float fn) {
    __shared__ uint32_t lh[8][KH];           // one copy per half-wave
    int t = threadIdx.x;
    int c = t >> 5;
    for (int j = t; j < 8 * KH; j += 256) ((uint32_t*)lh)[j] = 0u;
    __syncthreads();

    float lmin = 3.402823466e38f;
    int stride = gridDim.x * 256;
    for (int idx = blockIdx.x * 256 + t; idx < n4; idx += stride) {
        float4 v = x4[idx];
        lmin = fminf(fminf(v.x, v.y), fminf(fminf(v.z, v.w), lmin));
        bump(v.x, lh[c]); bump(v.y, lh[c]); bump(v.z, lh[c]); bump(v.w, lh[c]);
    }

    #pragma unroll
    for (int d = 32; d; d >>= 1) lmin = fminf(lmin, __shfl_down(lmin, d));
    __shared__ float wmin[4];
    if ((t & 63) == 0) wmin[t >> 6] = lmin;
    __syncthreads();

    // merge 8 copies -> global (t indexes the bin, 256 bins, 256 threads)
    uint32_t s = 0;
    #pragma unroll
    for (int cc = 0; cc < 8; ++cc) s += lh[cc][t];
    if (s) atomicAdd(&khist[t], s);
    if (t == 0)
        atomicMin(minkey, fkey(fminf(fminf(wmin[0], wmin[1]), fminf(wmin[2], wmin[3]))));

    // __syncthreads drains vmcnt -> all this block's global atomics performed
    __syncthreads();
    __shared__ int is_last;
    if (t == 0) {
        __threadfence();
        is_last = (atomicAdd(done1, 1u) == gridDim.x - 1) ? 1 : 0;
    }
    __syncthreads();
    if (!is_last) return;

    // ---------- table build: only the last block runs this ----------
    __shared__ float cnt[KH];
    __shared__ float hist[NBINS];
    __shared__ float ha[HLEN];
    __shared__ int s_ivmin;
    cnt[t] = (float)atomicAdd(&khist[t], 0u);          // coherent read
    if (t == 0) {
        float m = funkey(atomicMin(minkey, 0xFFFFFFFFu)); // coherent read (no-op min)
        s_ivmin = (int)(floorf(m) - 1.0f);
    }
    __syncthreads();
    int base = KOFF + 5 * s_ivmin;                     // key of reference bin 0

    if (t < NBINS) {
        float h = 0.0f;
        if (t == 0) {
            for (int kk = 0; kk < KH && kk <= base; ++kk) h += cnt[kk];
        } else if (t == NBINS - 1) {
            int lo = base + (NBINS - 1); if (lo < 0) lo = 0;
            for (int kk = lo; kk < KH; ++kk) h += cnt[kk];
        } else {
            int kk = base + t;
            if (kk >= 0 && kk < KH) h = cnt[kk];
        }
        hist[t] = h / fn;
    }
    __syncthreads();

    // inclusive Hillis-Steele scan over hist[0..199]
    for (int off = 1; off < NBINS; off <<= 1) {
        float v = 0.0f;
        if (t < NBINS && t >= off) v = hist[t - off];
        __syncthreads();
        if (t < NBINS && t >= off) hist[t] += v;
        __syncthreads();
    }

    if (t < HLEN) {
        float c_lo = (t == 0) ? 0.0f : hist[t - 1];
        ha[t] = hist[t + BPU - 1] - c_lo;              // c[t+5] - c[t]
    }
    __syncthreads();
    if (t < GLEN) gha[t] = make_float2((ha[t + 1] - ha[t]) * 5.0f, ha[t]);
    if (t == 0)  *vmn_out = (float)s_ivmin + 0.5f;     // vmin_new
}

// ---------------- kernel 2: per-element loss; last block finalizes -----------

__device__ inline double elem_loss(float v, float vmn, const float2* __restrict__ sgha) {
    float fi = fminf(fmaxf(floorf((v - vmn) * 5.0f), 0.0f), (float)(GLEN - 1));
    int i = (int)fi;
    float2 gh = sgha[i];                               // single ds_read_b64
    float nl = (v - (vmn + fi * 0.2f)) * gh.x + gh.y + 1e-8f;
    return (double)__logf(nl);
}

__global__ __launch_bounds__(256) void k_loss(const float4* __restrict__ x4, int n4,
                                              const float2* __restrict__ gha,
                                              const float*  __restrict__ vmn_p,
                                              double* __restrict__ acc,
                                              uint32_t* __restrict__ done2,
                                              float* __restrict__ out, double inv_n) {
    __shared__ float2 sgha[GLEN];
    int t = threadIdx.x;
    if (t < GLEN) sgha[t] = gha[t];
    float vmn = vmn_p[0];
    __syncthreads();

    double s = 0.0;
    int stride = gridDim.x * 256;
    for (int idx = blockIdx.x * 256 + t; idx < n4; idx += stride) {
        float4 v = x4[idx];
        s += elem_loss(v.x, vmn, sgha);
        s += elem_loss(v.y, vmn, sgha);
        s += elem_loss(v.z, vmn, sgha);
        s += elem_loss(v.w, vmn, sgha);
    }

    #pragma unroll
    for (int d = 32; d; d >>= 1) s += __shfl_down(s, d);
    __shared__ double wsum[4];
    if ((t & 63) == 0) wsum[t >> 6] = s;
    __syncthreads();
    if (t == 0) {
        atomicAdd(acc, wsum[0] + wsum[1] + wsum[2] + wsum[3]);
        __threadfence();
        if (atomicAdd(done2, 1u) == gridDim.x - 1) {
            double total = atomicAdd(acc, 0.0);        // coherent read of final sum
            out[0] = (float)(total * (-1.4426950408889634) * inv_n);
        }
    }
}

// ---------------- launch ------------------------------------------------------

extern "C" void kernel_launch(void* const* d_in, const int* in_sizes, int n_in,
                              void* d_out, int out_size, void* d_ws, size_t ws_size,
                              hipStream_t stream) {
    const float* x = (const float*)d_in[0];
    int n = in_sizes[0];
    int n4 = n >> 2;                    // shape is (32,64,128,128): divisible by 4
    float* out = (float*)d_out;

    uint8_t* ws = (uint8_t*)d_ws;
    uint32_t* khist  = (uint32_t*)ws;              // 256 u32  [0,1024)
    uint32_t* minkey = (uint32_t*)(ws + 1024);
    uint32_t* done1  = (uint32_t*)(ws + 1028);
    uint32_t* done2  = (uint32_t*)(ws + 1032);
    double*   acc    = (double*)(ws + 1040);
    float*    vmn    = (float*)(ws + 1048);
    float2*   gha    = (float2*)(ws + 1056);       // 195 float2

    k_init<<<1, 256, 0, stream>>>(khist, minkey, done1, done2, acc);
    k_min_hist<<<2048, 256, 0, stream>>>((const float4*)x, n4, khist, minkey, done1,
                                         gha, vmn, (float)n);
    k_loss<<<2048, 256, 0, stream>>>((const float4*)x, n4, gha, vmn, acc, done2,
                                     out, 1.0 / (double)n);
}

// Round 3
// 279.945 us; speedup vs baseline: 1.2020x; 1.2020x over previous
//
#include <hip/hip_runtime.h>
#include <stdint.h>

#define BPU    5
#define NBINS  200
#define GLEN   195   // NBINS - BPU
#define HLEN   196   // NBINS - BPU + 1
#define KH     256   // raw key-histogram bins; key = floor(x*5) + 128
#define NCOPY  32    // rotated LDS histogram copies

// ---------------- kernel 0: zero the raw histogram ---------------------------

__global__ __launch_bounds__(256) void k_init(uint32_t* khist) {
    khist[threadIdx.x] = 0u;
}

// ---------------- kernel 1: histogram only (no min needed) -------------------
// Lane-rotated copies: for copy c, key k is stored at slot ((k + c) & 255) in
// copy c's 1KB region. bank = (k + c) % 32 -> same-bin lanes spread across
// banks instead of serializing on one.

__device__ inline void bump(float v, uint32_t* __restrict__ lh, int off, int cbase) {
    int b = __float2int_rd(v * 5.0f);            // floor(5x)
    b = min(max(b, -128), 127);                  // safety clamp -> slot in [0,255]
    atomicAdd(&lh[cbase | ((b + off) & 255)], 1u);
}

__global__ __launch_bounds__(256) void k_hist(const float4* __restrict__ x4, int n4,
                                              uint32_t* __restrict__ khist) {
    __shared__ uint32_t lh[NCOPY * KH];          // 32 KB
    int t = threadIdx.x;
    int c = t & 31;
    int cbase = c << 8;
    int off = 128 + c;                           // key+rotation in one add
    for (int j = t; j < NCOPY * KH; j += 256) lh[j] = 0u;
    __syncthreads();

    const int stride = gridDim.x * 256;
    int i = blockIdx.x * 256 + t;
    for (; i + 3 * stride < n4; i += 4 * stride) {
        float4 v0 = x4[i];
        float4 v1 = x4[i + stride];
        float4 v2 = x4[i + 2 * stride];
        float4 v3 = x4[i + 3 * stride];
        bump(v0.x, lh, off, cbase); bump(v0.y, lh, off, cbase);
        bump(v0.z, lh, off, cbase); bump(v0.w, lh, off, cbase);
        bump(v1.x, lh, off, cbase); bump(v1.y, lh, off, cbase);
        bump(v1.z, lh, off, cbase); bump(v1.w, lh, off, cbase);
        bump(v2.x, lh, off, cbase); bump(v2.y, lh, off, cbase);
        bump(v2.z, lh, off, cbase); bump(v2.w, lh, off, cbase);
        bump(v3.x, lh, off, cbase); bump(v3.y, lh, off, cbase);
        bump(v3.z, lh, off, cbase); bump(v3.w, lh, off, cbase);
    }
    for (; i < n4; i += stride) {
        float4 v = x4[i];
        bump(v.x, lh, off, cbase); bump(v.y, lh, off, cbase);
        bump(v.z, lh, off, cbase); bump(v.w, lh, off, cbase);
    }
    __syncthreads();

    // merge: thread t owns key t; copy c stores key t at slot (t+c)&255
    uint32_t s = 0;
    #pragma unroll 8
    for (int cc = 0; cc < NCOPY; ++cc) s += lh[(cc << 8) | ((t + cc) & 255)];
    if (s) atomicAdd(&khist[t], s);
}

// ---------------- kernel 2: derive vmin from histogram; build A/B table ------

__global__ __launch_bounds__(256) void k_tables(const uint32_t* __restrict__ khist,
                                                float2* __restrict__ gAB,
                                                float*  __restrict__ off5_out,
                                                double* __restrict__ acc,
                                                uint32_t* __restrict__ done,
                                                float inv_n) {
    __shared__ float cnt[KH];
    __shared__ float hist[NBINS];
    __shared__ float ha[HLEN];
    __shared__ int s_k0;
    int t = threadIdx.x;
    uint32_t cv = khist[t];
    cnt[t] = (float)cv;
    if (t == 0) s_k0 = KH;
    __syncthreads();
    if (cv) atomicMin(&s_k0, t);                 // lowest nonempty key
    __syncthreads();

    // floor(min) = floordiv(k0 - 128, 5)  (exact: bins align with integers)
    int a = s_k0 - 128;
    int fd = (a >= 0) ? (a / 5) : -((-a + 4) / 5);
    int ivmin = fd - 1;                          // vmin = floor(min) - 1
    int base = 128 + 5 * ivmin;                  // key of reference bin 0

    if (t < NBINS) {
        float h = 0.0f;
        if (t == 0) {
            for (int kk = 0; kk < KH && kk <= base; ++kk) h += cnt[kk];
        } else if (t == NBINS - 1) {
            int lo = base + (NBINS - 1); if (lo < 0) lo = 0;
            for (int kk = lo; kk < KH; ++kk) h += cnt[kk];
        } else {
            int kk = base + t;
            if (kk >= 0 && kk < KH) h = cnt[kk];
        }
        hist[t] = h * inv_n;
    }
    __syncthreads();

    // inclusive Hillis-Steele scan over hist[0..199]
    for (int offs = 1; offs < NBINS; offs <<= 1) {
        float v = 0.0f;
        if (t < NBINS && t >= offs) v = hist[t - offs];
        __syncthreads();
        if (t < NBINS && t >= offs) hist[t] += v;
        __syncthreads();
    }

    if (t < HLEN) {
        float c_lo = (t == 0) ? 0.0f : hist[t - 1];
        ha[t] = hist[t + BPU - 1] - c_lo;        // c[t+5] - c[t]
    }
    __syncthreads();

    float vmn = (float)ivmin + 0.5f;             // vmin_new
    if (t < GLEN) {
        float A = (ha[t + 1] - ha[t]) * 5.0f;    // g[t]
        float left = vmn + (float)t * 0.2f;
        float B = ha[t] - left * A + 1e-8f;      // nloss = fma(x, A, B)
        gAB[t] = make_float2(A, B);
    }
    if (t == 0) { *off5_out = vmn * 5.0f; *acc = 0.0; *done = 0u; }
}

// ---------------- kernel 3: per-element loss; last block finalizes -----------

__device__ inline float el(float v, float off5, const float2* __restrict__ sAB) {
    float fi = fminf(fmaxf(fmaf(v, 5.0f, -off5), 0.0f), (float)(GLEN - 1));
    float2 ab = sAB[(int)fi];                    // hot-bin duplicates broadcast
    return __log2f(fmaf(v, ab.x, ab.y));
}

__global__ __launch_bounds__(256) void k_loss(const float4* __restrict__ x4, int n4,
                                              const float2* __restrict__ gAB,
                                              const float*  __restrict__ off5_p,
                                              double* __restrict__ acc,
                                              uint32_t* __restrict__ done,
                                              float* __restrict__ out, double inv_n) {
    __shared__ float2 sAB[GLEN];
    int t = threadIdx.x;
    if (t < GLEN) sAB[t] = gAB[t];
    float off5 = *off5_p;
    __syncthreads();

    float s0 = 0.f, s1 = 0.f, s2 = 0.f, s3 = 0.f;
    const int stride = gridDim.x * 256;
    int i = blockIdx.x * 256 + t;
    for (; i + 3 * stride < n4; i += 4 * stride) {
        float4 v0 = x4[i];
        float4 v1 = x4[i + stride];
        float4 v2 = x4[i + 2 * stride];
        float4 v3 = x4[i + 3 * stride];
        s0 += el(v0.x, off5, sAB) + el(v0.y, off5, sAB)
            + el(v0.z, off5, sAB) + el(v0.w, off5, sAB);
        s1 += el(v1.x, off5, sAB) + el(v1.y, off5, sAB)
            + el(v1.z, off5, sAB) + el(v1.w, off5, sAB);
        s2 += el(v2.x, off5, sAB) + el(v2.y, off5, sAB)
            + el(v2.z, off5, sAB) + el(v2.w, off5, sAB);
        s3 += el(v3.x, off5, sAB) + el(v3.y, off5, sAB)
            + el(v3.z, off5, sAB) + el(v3.w, off5, sAB);
    }
    for (; i < n4; i += stride) {
        float4 v = x4[i];
        s0 += el(v.x, off5, sAB) + el(v.y, off5, sAB)
            + el(v.z, off5, sAB) + el(v.w, off5, sAB);
    }

    double d = ((double)s0 + (double)s1) + ((double)s2 + (double)s3);
    #pragma unroll
    for (int dd = 32; dd; dd >>= 1) d += __shfl_down(d, dd);
    __shared__ double wsum[4];
    if ((t & 63) == 0) wsum[t >> 6] = d;
    __syncthreads();
    if (t == 0) {
        atomicAdd(acc, (wsum[0] + wsum[1]) + (wsum[2] + wsum[3]));
        __threadfence();
        if (atomicAdd(done, 1u) == gridDim.x - 1) {
            double total = atomicAdd(acc, 0.0);  // coherent read of final sum
            out[0] = (float)(-total * inv_n);    // rloss/n = -sum(log2)/n
        }
    }
}

// ---------------- launch ------------------------------------------------------

extern "C" void kernel_launch(void* const* d_in, const int* in_sizes, int n_in,
                              void* d_out, int out_size, void* d_ws, size_t ws_size,
                              hipStream_t stream) {
    const float* x = (const float*)d_in[0];
    int n = in_sizes[0];
    int n4 = n >> 2;                             // (32,64,128,128): divisible by 4
    float* out = (float*)d_out;

    uint8_t* ws = (uint8_t*)d_ws;
    uint32_t* khist = (uint32_t*)ws;             // 256 u32  [0,1024)
    uint32_t* done  = (uint32_t*)(ws + 1024);
    double*   acc   = (double*)(ws + 1032);
    float*    off5  = (float*)(ws + 1040);
    float2*   gAB   = (float2*)(ws + 1056);      // 195 float2

    k_init<<<1, 256, 0, stream>>>(khist);
    // 32 KB LDS/block -> 4 blocks/CU; 1024 blocks = exactly 4 per CU
    k_hist<<<1024, 256, 0, stream>>>((const float4*)x, n4, khist);
    k_tables<<<1, 256, 0, stream>>>(khist, gAB, off5, acc, done, 1.0f / (float)n);
    k_loss<<<2048, 256, 0, stream>>>((const float4*)x, n4, gAB, off5, acc, done,
                                     out, 1.0 / (double)n);
}